// Round 3
// baseline (360.559 us; speedup 1.0000x reference)
//
#include <hip/hip_runtime.h>

// Shapes (fixed per setup_inputs): n=1, C=256, t=8, h=64, w=64, heads=8, S=134
#define SS   134
#define HWP  4096     // h*w
#define THW  32768    // t*h*w

typedef float f32x4 __attribute__((ext_vector_type(4)));
typedef short bf16x8 __attribute__((ext_vector_type(8)));
typedef short bf16x4 __attribute__((ext_vector_type(4)));

__device__ __forceinline__ unsigned short f2bf(float f) {
  unsigned int u = __float_as_uint(f);
  u += 0x7fff + ((u >> 16) & 1);  // RNE (inputs are finite normals)
  return (unsigned short)(u >> 16);
}

// ---------------------------------------------------------------------------
// W -> bf16, once (was re-converted per conv block = 67M redundant f2bf).
// Wbf lives in d_out (128 KB): attn_th fully overwrites O later, and the
// stream order w2bf -> conv -> attn_th makes the aliasing safe.
// ---------------------------------------------------------------------------
__global__ __launch_bounds__(256) void w2bf(const float* __restrict__ W,
                                            unsigned short* __restrict__ Wbf) {
  const int i = (blockIdx.x * 256 + threadIdx.x) * 4;  // grid 64 -> 65536
  const float4 w4 = *(const float4*)&W[i];
  bf16x4 b;
  b.x = (short)f2bf(w4.x);
  b.y = (short)f2bf(w4.y);
  b.z = (short)f2bf(w4.z);
  b.w = (short)f2bf(w4.w);
  *(bf16x4*)&Wbf[i] = b;
}

// ---------------------------------------------------------------------------
// 1x1 conv as bf16-MFMA GEMM: PV[o][x] = sum_c W[o][c] * V[c][x] + bias[o]
// v3: W staged from precomputed bf16 (pure 16B copies, no per-block f2bf).
// ---------------------------------------------------------------------------
__global__ __launch_bounds__(256) void conv1x1_v3(
    const float* __restrict__ V, const unsigned short* __restrict__ Wbf,
    const float* __restrict__ bias, float* __restrict__ PV) {
  __shared__ unsigned short sW[256 * 40];  // [o][c-k0], bf16, row stride 40
  __shared__ unsigned short sV[32 * 40];   // [x][c-k0], bf16 (transposed)
  const int tid = threadIdx.x;
  const int x0 = blockIdx.x * 32;
  const int lane = tid & 63;
  const int wv = tid >> 6;   // wave 0..3
  const int m = lane & 15;   // MFMA free-dim index
  const int q = lane >> 4;   // MFMA quad 0..3

  f32x4 acc[4][2];
#pragma unroll
  for (int i = 0; i < 4; ++i)
#pragma unroll
    for (int j = 0; j < 2; ++j)
      acc[i][j] = (f32x4){0.f, 0.f, 0.f, 0.f};

  for (int k0 = 0; k0 < 256; k0 += 32) {
    // stage W slice [256 o][32 c] bf16: 1024 short8 copies
#pragma unroll
    for (int r = 0; r < 4; ++r) {
      const int s8 = r * 256 + tid;   // short8 slot 0..1023
      const int o = s8 >> 2;
      const int c8 = (s8 & 3) * 8;
      *(bf16x8*)&sW[o * 40 + c8] = *(const bf16x8*)&Wbf[o * 256 + k0 + c8];
    }
    {
      const int c = tid >> 3;          // 0..31
      const int x4 = (tid & 7) * 4;    // 0..28
      const float4 v4 = *(const float4*)&V[(size_t)(k0 + c) * THW + x0 + x4];
      sV[(x4 + 0) * 40 + c] = f2bf(v4.x);
      sV[(x4 + 1) * 40 + c] = f2bf(v4.y);
      sV[(x4 + 2) * 40 + c] = f2bf(v4.z);
      sV[(x4 + 3) * 40 + c] = f2bf(v4.w);
    }
    __syncthreads();
    bf16x8 fa[4], fb[2];
#pragma unroll
    for (int i = 0; i < 4; ++i)
      fa[i] = *(const bf16x8*)&sW[(wv * 64 + i * 16 + m) * 40 + q * 8];
#pragma unroll
    for (int j = 0; j < 2; ++j)
      fb[j] = *(const bf16x8*)&sV[(j * 16 + m) * 40 + q * 8];
#pragma unroll
    for (int i = 0; i < 4; ++i)
#pragma unroll
      for (int j = 0; j < 2; ++j)
        acc[i][j] = __builtin_amdgcn_mfma_f32_16x16x32_bf16(fa[i], fb[j], acc[i][j], 0, 0, 0);
    __syncthreads();
  }

#pragma unroll
  for (int i = 0; i < 4; ++i) {
#pragma unroll
    for (int r = 0; r < 4; ++r) {
      const int o = wv * 64 + i * 16 + q * 4 + r;
      const float b = bias[o];
#pragma unroll
      for (int j = 0; j < 2; ++j)
        PV[(size_t)o * THW + x0 + j * 16 + m] = acc[i][j][r] + b;
    }
  }
}

// ---------------------------------------------------------------------------
// t + h axes, v4: same fully-coalesced structure as v3 (FETCH 65MB, conflict
// free), but 1024 threads/block (16 waves = 4 waves/SIMD, was 2/SIMD at 20%
// occupancy). v3 was latency-bound: VALU 13%, DS 12%, L1 ~26%, nothing
// saturated -> not enough waves to hide L2/L3 latency. Zero traffic change;
// identical accumulation order (bitwise-same numerics).
//   Block = (hd, tq, qb of 16 q), grid 256, 1024 threads (1 blk/CU, 128KB LDS)
//   lane: w4 = (lane&15)*4 (full w via f32x4), cl = lane>>4 (4 c)
//   wave wv 0..15: ch = wv&1 (c half), qg = wv>>1 (0..7)
//   q = qb*16 + qg*2 + qi (qi 0..1);  c = ch*16 + g*4 + cl (g 0..3)
//   acc[2 qi][4 g] f32x4 over w.
// ---------------------------------------------------------------------------
__global__ __launch_bounds__(1024, 4) void attn_th(
    const float* __restrict__ A, const float* __restrict__ PV,
    float* __restrict__ O) {
  const int b = blockIdx.x;  // hd + 8*(qb + 4*tq), grid 256
  const int hd = b & 7;      // all blocks of one head share b%8 -> same XCD
  const int qb = (b >> 3) & 3;
  const int tq = b >> 5;  // 0..7
  const int tid = threadIdx.x;
  const int lane = tid & 63;
  const int wv = tid >> 6;         // 0..15
  const int w4 = (lane & 15) * 4;  // w float-offset (f32x4)
  const int cl = lane >> 4;        // 0..3
  const int ch = wv & 1;           // c half
  const int qg = wv >> 1;          // 0..7
  const int q0 = qb * 16 + qg * 2;

  __shared__ float slab[2][8 * 32 * 64];  // [buf][pp][c][w]

  const float* __restrict__ Ab = A + (size_t)hd * SS * THW + (size_t)tq * HWP;
  const size_t pvh = (size_t)hd * 32 * THW;
  const float* __restrict__ PVh = PV + pvh;

  f32x4 acc[2][4];  // [qi][g]
#pragma unroll
  for (int i = 0; i < 2; ++i)
#pragma unroll
    for (int j = 0; j < 4; ++j)
      acc[i][j] = (f32x4){0.f, 0.f, 0.f, 0.f};

  // staging map: thread handles pp = pp0 + 2r (r=0..3), fixed (c_s, w4s)
  const int c_s = (tid >> 4) & 31;
  const int w4s = (tid & 15) * 4;
  const int pp0 = tid >> 9;  // 0..1
  const float* __restrict__ pvstage =
      PVh + (size_t)c_s * THW + (size_t)tq * HWP + w4s;
  const int sbase = c_s * 64 + w4s;  // LDS float offset within a pp-plane

  // issue chunk-0 prefetch (p = 0..7) early; overlaps t-axis compute
  f32x4 stg[4];
#pragma unroll
  for (int r = 0; r < 4; ++r)
    stg[r] = *(const f32x4*)&pvstage[(pp0 + 2 * r) * 64];

  // ---- t axis (pure streaming, fully coalesced, no reuse) ----
  for (int s = 0; s < 8; ++s) {
#pragma unroll
    for (int qi = 0; qi < 2; ++qi) {
      const int q = q0 + qi;
      const f32x4 a = *(const f32x4*)&Ab[(size_t)s * THW + q * 64 + w4];
#pragma unroll
      for (int g = 0; g < 4; ++g) {
        const int c = ch * 16 + g * 4 + cl;
        const f32x4 v =
            *(const f32x4*)&PVh[(size_t)c * THW + (size_t)s * HWP + q * 64 + w4];
        acc[qi][g] += a * v;
      }
    }
  }

  // write chunk 0 into buf 0
#pragma unroll
  for (int r = 0; r < 4; ++r)
    *(f32x4*)&slab[0][(pp0 + 2 * r) * 2048 + sbase] = stg[r];
  __syncthreads();

  // ---- h axis: 8 chunks of 8 p, double-buffered ----
  for (int ck = 0; ck < 8; ++ck) {
    const int cur = ck & 1;
    if (ck < 7) {
      // issue next chunk's global loads now; they complete under the FMAs
#pragma unroll
      for (int r = 0; r < 4; ++r)
        stg[r] = *(const f32x4*)&pvstage[((ck + 1) * 8 + pp0 + 2 * r) * 64];
    }
#pragma unroll
    for (int pp = 0; pp < 8; ++pp) {
      const int p = ck * 8 + pp;
      f32x4 a[2];
#pragma unroll
      for (int qi = 0; qi < 2; ++qi) {
        const int q = q0 + qi;
        const int row = p - (q < p ? 1 : 0);  // 0..63 (p==q load masked)
        f32x4 av = *(const f32x4*)&Ab[(size_t)(8 + row) * THW + q * 64 + w4];
        if (q == p) av = (f32x4){0.f, 0.f, 0.f, 0.f};
        a[qi] = av;
      }
      f32x4 v[4];
#pragma unroll
      for (int g = 0; g < 4; ++g)
        v[g] = *(const f32x4*)&slab[cur][pp * 2048 + (ch * 16 + g * 4 + cl) * 64 + w4];
#pragma unroll
      for (int qi = 0; qi < 2; ++qi)
#pragma unroll
        for (int g = 0; g < 4; ++g)
          acc[qi][g] += a[qi] * v[g];
    }
    __syncthreads();
    if (ck < 7) {
#pragma unroll
      for (int r = 0; r < 4; ++r)
        *(f32x4*)&slab[cur ^ 1][(pp0 + 2 * r) * 2048 + sbase] = stg[r];
      __syncthreads();
    }
  }

  // ---- store ----
#pragma unroll
  for (int qi = 0; qi < 2; ++qi) {
    const int q = q0 + qi;
#pragma unroll
    for (int g = 0; g < 4; ++g) {
      const int c = ch * 16 + g * 4 + cl;
      *(f32x4*)&O[pvh + (size_t)c * THW + (size_t)tq * HWP + q * 64 + w4] =
          acc[qi][g];
    }
  }
}

// ---------------------------------------------------------------------------
// w axis, read-modify-write on O. (unchanged this round; counters next round)
// ---------------------------------------------------------------------------
__global__ __launch_bounds__(256) void attn_w(
    const float* __restrict__ A, const float* __restrict__ PV,
    float* __restrict__ O) {
  const int b = blockIdx.x;  // hb + 16*tq + 128*hd, grid 1024
  const int hb = b & 15;
  const int tq = (b >> 4) & 7;
  const int hd = b >> 7;
  const int tid = threadIdx.x;
  const int wq = tid & 63;
  const int cg = tid >> 6;  // 0..3
  const int h0 = hb * 4;

  __shared__ float slab[32 * 64 * 4];  // [c][pw][h4]

  const float* __restrict__ Ab = A + (size_t)hd * SS * THW + (size_t)tq * HWP;
  const size_t pvh = (size_t)hd * 32 * THW;

  // stage pv w-slab (transpose w<->h minor dims)
#pragma unroll 4
  for (int i = 0; i < 8; ++i) {
    const int fid = tid + i * 256;     // 0..2047
    const int w4s = (fid & 15) * 4;    // 0..60
    const int h = (fid >> 4) & 3;      // 0..3
    const int c = fid >> 6;            // 0..31
    const f32x4 v =
        *(const f32x4*)&PV[pvh + (size_t)c * THW + (size_t)tq * HWP + (h0 + h) * 64 + w4s];
    slab[(c * 64 + w4s + 0) * 4 + h] = v.x;
    slab[(c * 64 + w4s + 1) * 4 + h] = v.y;
    slab[(c * 64 + w4s + 2) * 4 + h] = v.z;
    slab[(c * 64 + w4s + 3) * 4 + h] = v.w;
  }

  // prefetch current O tile (RMW) while staging completes
  f32x4 racc[8];
#pragma unroll
  for (int ci = 0; ci < 8; ++ci) {
    const int c = cg + ci * 4;
    f32x4 r;
#pragma unroll
    for (int hh = 0; hh < 4; ++hh)
      r[hh] = O[pvh + (size_t)c * THW + (size_t)tq * HWP + (h0 + hh) * 64 + wq];
    racc[ci] = r;
  }
  __syncthreads();

#pragma unroll 2
  for (int p = 0; p < 64; ++p) {
    const int row = 71 + p - (wq <= p ? 1 : 0);  // 70..133, in-bounds always
    const float* pa = Ab + (size_t)row * THW + h0 * 64 + wq;
    f32x4 a;
    a.x = pa[0];
    a.y = pa[64];
    a.z = pa[128];
    a.w = pa[192];
    if (p == wq) a = (f32x4){0.f, 0.f, 0.f, 0.f};
#pragma unroll
    for (int ci = 0; ci < 8; ++ci) {
      const f32x4 v = *(const f32x4*)&slab[(cg + ci * 4) * 256 + p * 4];
      racc[ci] += a * v;
    }
  }

  // ---- store (RMW result) ----
#pragma unroll
  for (int ci = 0; ci < 8; ++ci) {
    const int c = cg + ci * 4;
#pragma unroll
    for (int hh = 0; hh < 4; ++hh)
      O[pvh + (size_t)c * THW + (size_t)tq * HWP + (h0 + hh) * 64 + wq] = racc[ci][hh];
  }
}

extern "C" void kernel_launch(void* const* d_in, const int* in_sizes, int n_in,
                              void* d_out, int out_size, void* d_ws, size_t ws_size,
                              hipStream_t stream) {
  const float* A = (const float*)d_in[0];     // [8*134][8][64][64]
  const float* V = (const float*)d_in[1];     // [256][8][64][64]
  const float* W = (const float*)d_in[2];     // [256][256] (o, c)
  const float* bias = (const float*)d_in[3];  // [256]
  float* out = (float*)d_out;                 // [256][8][64][64]
  float* pv = (float*)d_ws;                   // 32 MB scratch: pv[o][t][h][w]

  unsigned short* Wbf = (unsigned short*)d_out;  // temp 128 KB, dead after conv

  w2bf<<<dim3(64), 256, 0, stream>>>(W, Wbf);
  conv1x1_v3<<<dim3(1024), 256, 0, stream>>>(V, Wbf, bias, pv);
  attn_th<<<dim3(256), 1024, 0, stream>>>(A, pv, out);
  attn_w<<<dim3(1024), 256, 0, stream>>>(A, pv, out);
}

// Round 4
// 357.128 us; speedup vs baseline: 1.0096x; 1.0096x over previous
//
#include <hip/hip_runtime.h>

// Shapes (fixed per setup_inputs): n=1, C=256, t=8, h=64, w=64, heads=8, S=134
#define SS   134
#define HWP  4096     // h*w
#define THW  32768    // t*h*w

typedef float f32x4 __attribute__((ext_vector_type(4)));
typedef short bf16x8 __attribute__((ext_vector_type(8)));
typedef short bf16x4 __attribute__((ext_vector_type(4)));

__device__ __forceinline__ unsigned short f2bf(float f) {
  unsigned int u = __float_as_uint(f);
  u += 0x7fff + ((u >> 16) & 1);  // RNE (inputs are finite normals)
  return (unsigned short)(u >> 16);
}

// ---------------------------------------------------------------------------
// W -> bf16, once. Wbf lives in d_out (128 KB): attn_th fully overwrites O
// later, stream order makes the aliasing safe.
// ---------------------------------------------------------------------------
__global__ __launch_bounds__(256) void w2bf(const float* __restrict__ W,
                                            unsigned short* __restrict__ Wbf) {
  const int i = (blockIdx.x * 256 + threadIdx.x) * 4;  // grid 64 -> 65536
  const float4 w4 = *(const float4*)&W[i];
  bf16x4 b;
  b.x = (short)f2bf(w4.x);
  b.y = (short)f2bf(w4.y);
  b.z = (short)f2bf(w4.z);
  b.w = (short)f2bf(w4.w);
  *(bf16x4*)&Wbf[i] = b;
}

// ---------------------------------------------------------------------------
// 1x1 conv as bf16-MFMA GEMM: PV[o][x] = sum_c W[o][c] * V[c][x] + bias[o]
// (unchanged from R2)
// ---------------------------------------------------------------------------
__global__ __launch_bounds__(256) void conv1x1_v3(
    const float* __restrict__ V, const unsigned short* __restrict__ Wbf,
    const float* __restrict__ bias, float* __restrict__ PV) {
  __shared__ unsigned short sW[256 * 40];  // [o][c-k0], bf16, row stride 40
  __shared__ unsigned short sV[32 * 40];   // [x][c-k0], bf16 (transposed)
  const int tid = threadIdx.x;
  const int x0 = blockIdx.x * 32;
  const int lane = tid & 63;
  const int wv = tid >> 6;   // wave 0..3
  const int m = lane & 15;   // MFMA free-dim index
  const int q = lane >> 4;   // MFMA quad 0..3

  f32x4 acc[4][2];
#pragma unroll
  for (int i = 0; i < 4; ++i)
#pragma unroll
    for (int j = 0; j < 2; ++j)
      acc[i][j] = (f32x4){0.f, 0.f, 0.f, 0.f};

  for (int k0 = 0; k0 < 256; k0 += 32) {
    // stage W slice [256 o][32 c] bf16: 1024 short8 copies
#pragma unroll
    for (int r = 0; r < 4; ++r) {
      const int s8 = r * 256 + tid;   // short8 slot 0..1023
      const int o = s8 >> 2;
      const int c8 = (s8 & 3) * 8;
      *(bf16x8*)&sW[o * 40 + c8] = *(const bf16x8*)&Wbf[o * 256 + k0 + c8];
    }
    {
      const int c = tid >> 3;          // 0..31
      const int x4 = (tid & 7) * 4;    // 0..28
      const float4 v4 = *(const float4*)&V[(size_t)(k0 + c) * THW + x0 + x4];
      sV[(x4 + 0) * 40 + c] = f2bf(v4.x);
      sV[(x4 + 1) * 40 + c] = f2bf(v4.y);
      sV[(x4 + 2) * 40 + c] = f2bf(v4.z);
      sV[(x4 + 3) * 40 + c] = f2bf(v4.w);
    }
    __syncthreads();
    bf16x8 fa[4], fb[2];
#pragma unroll
    for (int i = 0; i < 4; ++i)
      fa[i] = *(const bf16x8*)&sW[(wv * 64 + i * 16 + m) * 40 + q * 8];
#pragma unroll
    for (int j = 0; j < 2; ++j)
      fb[j] = *(const bf16x8*)&sV[(j * 16 + m) * 40 + q * 8];
#pragma unroll
    for (int i = 0; i < 4; ++i)
#pragma unroll
      for (int j = 0; j < 2; ++j)
        acc[i][j] = __builtin_amdgcn_mfma_f32_16x16x32_bf16(fa[i], fb[j], acc[i][j], 0, 0, 0);
    __syncthreads();
  }

#pragma unroll
  for (int i = 0; i < 4; ++i) {
#pragma unroll
    for (int r = 0; r < 4; ++r) {
      const int o = wv * 64 + i * 16 + q * 4 + r;
      const float b = bias[o];
#pragma unroll
      for (int j = 0; j < 2; ++j)
        PV[(size_t)o * THW + x0 + j * 16 + m] = acc[i][j][r] + b;
    }
  }
}

// ---------------------------------------------------------------------------
// t + h axes, v5: fully-coalesced (R2 structure) + REAL occupancy fix.
// R2 was latency-bound at 1 blk/CU (128KB LDS, 2 waves/SIMD, VALU 13% =
// 1.6 live waves x ~8% duty). R3's 1024-thr attempt spilled (VGPR 64,
// WRITE +30MB). v5: keep 512 thr / VGPR-128 regime, halve LDS to 64KB by
// splitting the c-dim across blocks -> 2 blk/CU = 4 waves/SIMD, no spill.
//   Block = (hd, tq, qb of 16 q, chb of 16 c), grid 512, 512 thr.
//   lane: w4 = (lane&15)*4 (full w via f32x4), cl = lane>>4 (4 c)
//   wave wv 0..7: q = qb*16 + wv*2 + qi (qi 0..1)
//   c = chb*16 + g*4 + cl (g 0..3).  acc[2 qi][4 g] f32x4 over w.
// h-axis PV chunk double-buffered in LDS ([2][8 pp][16 c][64 w] = 64 KB),
// global->reg prefetch issued before compute so staging hides under FMA.
// Accumulation order per output unchanged (s=0..7 then p=0..63): bitwise
// identical to R2. A_h L2-reads duplicate x2 (c-split) but HBM-unique
// unchanged; staging/t-axis totals unchanged.
// ---------------------------------------------------------------------------
__global__ __launch_bounds__(512, 4) void attn_th(
    const float* __restrict__ A, const float* __restrict__ PV,
    float* __restrict__ O) {
  const int b = blockIdx.x;  // hd + 8*(chb + 2*(qb + 4*tq)), grid 512
  const int hd = b & 7;      // all blocks of one head share b%8 -> same XCD
  const int chb = (b >> 3) & 1;
  const int qb = (b >> 4) & 3;
  const int tq = b >> 6;  // 0..7
  const int tid = threadIdx.x;
  const int lane = tid & 63;
  const int wv = tid >> 6;         // 0..7
  const int w4 = (lane & 15) * 4;  // w float-offset (f32x4)
  const int cl = lane >> 4;        // 0..3
  const int q0 = qb * 16 + wv * 2;
  const int c0 = chb * 16;

  __shared__ float slab[2][8 * 16 * 64];  // [buf][pp][c][w] = 64 KB

  const float* __restrict__ Ab = A + (size_t)hd * SS * THW + (size_t)tq * HWP;
  const size_t pvh = (size_t)hd * 32 * THW;
  const float* __restrict__ PVh = PV + pvh;

  f32x4 acc[2][4];  // [qi][g]
#pragma unroll
  for (int i = 0; i < 2; ++i)
#pragma unroll
    for (int j = 0; j < 4; ++j)
      acc[i][j] = (f32x4){0.f, 0.f, 0.f, 0.f};

  // staging map: thread covers pp = pp0 + 2r (r=0..3) at fixed (c_s, w4s)
  const int w4s = (tid & 15) * 4;
  const int c_s = (tid >> 4) & 15;
  const int pp0 = tid >> 8;  // 0..1
  const float* __restrict__ pvstage =
      PVh + (size_t)(c0 + c_s) * THW + (size_t)tq * HWP + w4s;
  const int sbase = c_s * 64 + w4s;  // float offset within a pp plane (16c*64w)

  // issue chunk-0 prefetch (p = 0..7) early; overlaps t-axis compute
  f32x4 stg[4];
#pragma unroll
  for (int r = 0; r < 4; ++r)
    stg[r] = *(const f32x4*)&pvstage[(pp0 + 2 * r) * 64];

  // ---- t axis (pure streaming, fully coalesced, no reuse) ----
  for (int s = 0; s < 8; ++s) {
#pragma unroll
    for (int qi = 0; qi < 2; ++qi) {
      const int q = q0 + qi;
      const f32x4 a = *(const f32x4*)&Ab[(size_t)s * THW + q * 64 + w4];
#pragma unroll
      for (int g = 0; g < 4; ++g) {
        const int c = c0 + g * 4 + cl;
        const f32x4 v =
            *(const f32x4*)&PVh[(size_t)c * THW + (size_t)s * HWP + q * 64 + w4];
        acc[qi][g] += a * v;
      }
    }
  }

  // write chunk 0 into buf 0
#pragma unroll
  for (int r = 0; r < 4; ++r)
    *(f32x4*)&slab[0][(pp0 + 2 * r) * 1024 + sbase] = stg[r];
  __syncthreads();

  // ---- h axis: 8 chunks of 8 p, double-buffered ----
  for (int ck = 0; ck < 8; ++ck) {
    const int cur = ck & 1;
    if (ck < 7) {
      // issue next chunk's global loads now; they complete under the FMAs
#pragma unroll
      for (int r = 0; r < 4; ++r)
        stg[r] = *(const f32x4*)&pvstage[((ck + 1) * 8 + pp0 + 2 * r) * 64];
    }
#pragma unroll
    for (int pp = 0; pp < 8; ++pp) {
      const int p = ck * 8 + pp;
      f32x4 a[2];
#pragma unroll
      for (int qi = 0; qi < 2; ++qi) {
        const int q = q0 + qi;
        const int row = p - (q < p ? 1 : 0);  // 0..63 (p==q load masked)
        f32x4 av = *(const f32x4*)&Ab[(size_t)(8 + row) * THW + q * 64 + w4];
        if (q == p) av = (f32x4){0.f, 0.f, 0.f, 0.f};
        a[qi] = av;
      }
      f32x4 v[4];
#pragma unroll
      for (int g = 0; g < 4; ++g)
        v[g] = *(const f32x4*)&slab[cur][pp * 1024 + (g * 4 + cl) * 64 + w4];
#pragma unroll
      for (int qi = 0; qi < 2; ++qi)
#pragma unroll
        for (int g = 0; g < 4; ++g)
          acc[qi][g] += a[qi] * v[g];
    }
    __syncthreads();
    if (ck < 7) {
#pragma unroll
      for (int r = 0; r < 4; ++r)
        *(f32x4*)&slab[cur ^ 1][(pp0 + 2 * r) * 1024 + sbase] = stg[r];
      __syncthreads();
    }
  }

  // ---- store ----
#pragma unroll
  for (int qi = 0; qi < 2; ++qi) {
    const int q = q0 + qi;
#pragma unroll
    for (int g = 0; g < 4; ++g) {
      const int c = c0 + g * 4 + cl;
      *(f32x4*)&O[pvh + (size_t)c * THW + (size_t)tq * HWP + q * 64 + w4] =
          acc[qi][g];
    }
  }
}

// ---------------------------------------------------------------------------
// w axis, read-modify-write on O. (unchanged; counters expected next round)
// ---------------------------------------------------------------------------
__global__ __launch_bounds__(256) void attn_w(
    const float* __restrict__ A, const float* __restrict__ PV,
    float* __restrict__ O) {
  const int b = blockIdx.x;  // hb + 16*tq + 128*hd, grid 1024
  const int hb = b & 15;
  const int tq = (b >> 4) & 7;
  const int hd = b >> 7;
  const int tid = threadIdx.x;
  const int wq = tid & 63;
  const int cg = tid >> 6;  // 0..3
  const int h0 = hb * 4;

  __shared__ float slab[32 * 64 * 4];  // [c][pw][h4]

  const float* __restrict__ Ab = A + (size_t)hd * SS * THW + (size_t)tq * HWP;
  const size_t pvh = (size_t)hd * 32 * THW;

  // stage pv w-slab (transpose w<->h minor dims)
#pragma unroll 4
  for (int i = 0; i < 8; ++i) {
    const int fid = tid + i * 256;     // 0..2047
    const int w4s = (fid & 15) * 4;    // 0..60
    const int h = (fid >> 4) & 3;      // 0..3
    const int c = fid >> 6;            // 0..31
    const f32x4 v =
        *(const f32x4*)&PV[pvh + (size_t)c * THW + (size_t)tq * HWP + (h0 + h) * 64 + w4s];
    slab[(c * 64 + w4s + 0) * 4 + h] = v.x;
    slab[(c * 64 + w4s + 1) * 4 + h] = v.y;
    slab[(c * 64 + w4s + 2) * 4 + h] = v.z;
    slab[(c * 64 + w4s + 3) * 4 + h] = v.w;
  }

  // prefetch current O tile (RMW) while staging completes
  f32x4 racc[8];
#pragma unroll
  for (int ci = 0; ci < 8; ++ci) {
    const int c = cg + ci * 4;
    f32x4 r;
#pragma unroll
    for (int hh = 0; hh < 4; ++hh)
      r[hh] = O[pvh + (size_t)c * THW + (size_t)tq * HWP + (h0 + hh) * 64 + wq];
    racc[ci] = r;
  }
  __syncthreads();

#pragma unroll 2
  for (int p = 0; p < 64; ++p) {
    const int row = 71 + p - (wq <= p ? 1 : 0);  // 70..133, in-bounds always
    const float* pa = Ab + (size_t)row * THW + h0 * 64 + wq;
    f32x4 a;
    a.x = pa[0];
    a.y = pa[64];
    a.z = pa[128];
    a.w = pa[192];
    if (p == wq) a = (f32x4){0.f, 0.f, 0.f, 0.f};
#pragma unroll
    for (int ci = 0; ci < 8; ++ci) {
      const f32x4 v = *(const f32x4*)&slab[(cg + ci * 4) * 256 + p * 4];
      racc[ci] += a * v;
    }
  }

  // ---- store (RMW result) ----
#pragma unroll
  for (int ci = 0; ci < 8; ++ci) {
    const int c = cg + ci * 4;
#pragma unroll
    for (int hh = 0; hh < 4; ++hh)
      O[pvh + (size_t)c * THW + (size_t)tq * HWP + (h0 + hh) * 64 + wq] = racc[ci][hh];
  }
}

extern "C" void kernel_launch(void* const* d_in, const int* in_sizes, int n_in,
                              void* d_out, int out_size, void* d_ws, size_t ws_size,
                              hipStream_t stream) {
  const float* A = (const float*)d_in[0];     // [8*134][8][64][64]
  const float* V = (const float*)d_in[1];     // [256][8][64][64]
  const float* W = (const float*)d_in[2];     // [256][256] (o, c)
  const float* bias = (const float*)d_in[3];  // [256]
  float* out = (float*)d_out;                 // [256][8][64][64]
  float* pv = (float*)d_ws;                   // 32 MB scratch: pv[o][t][h][w]

  unsigned short* Wbf = (unsigned short*)d_out;  // temp 128 KB, dead after conv

  w2bf<<<dim3(64), 256, 0, stream>>>(W, Wbf);
  conv1x1_v3<<<dim3(1024), 256, 0, stream>>>(V, Wbf, bias, pv);
  attn_th<<<dim3(512), 512, 0, stream>>>(A, pv, out);
  attn_w<<<dim3(1024), 256, 0, stream>>>(A, pv, out);
}